// Round 2
// baseline (473.972 us; speedup 1.0000x reference)
//
#include <hip/hip_runtime.h>
#include <hip/hip_bf16.h>
#include <math.h>

constexpr int SEQ   = 512;
constexpr int HIDC  = 1024;
constexpr int NH    = 16;
constexpr int HDIM  = 64;
constexpr int NFREQ = 33;   // rfft bins for n=64
constexpr int NF2V  = 66;   // packed (Re|Im) length

// dtype-agnostic input load: f32 ? float : bf16
__device__ __forceinline__ float ldin(const void* p, int i, int f32) {
    if (f32) return ((const float*)p)[i];
    return __bfloat162float(((const __hip_bfloat16*)p)[i]);
}

// ---------------- K0: dtype sniff ----------------
// Interpret first 512 half-words of Wq as bf16. If the underlying data is
// fp32, the even halves are fp32 mantissa bits -> random bf16 exponents ->
// ~47% decode to |v|>=128 (or inf/nan). True bf16 weights are |w|<~0.3.
__global__ void sniff_kernel(const void* w, int* flag) {
    __shared__ int cnt;
    if (threadIdx.x == 0) cnt = 0;
    __syncthreads();
    const unsigned short* h = (const unsigned short*)w;
    int bad = 0;
    for (int i = threadIdx.x; i < 512; i += 256) {
        const unsigned short v = h[i];
        const int ex = (v >> 7) & 0xFF;   // bf16 exponent field
        if (ex >= 134) bad++;             // |x| >= 128 (or inf/nan)
    }
    atomicAdd(&cnt, bad);
    __syncthreads();
    if (threadIdx.x == 0) flag[0] = (cnt > 32) ? 1 : 0;
}

// ---------------- K1: fused QKV projection (x @ [Wq|Wk|Wv] + b) ----------------
__global__ __launch_bounds__(256) void qkv_kernel(
    const void* __restrict__ x,
    const void* __restrict__ Wq, const void* __restrict__ bq,
    const void* __restrict__ Wk, const void* __restrict__ bk,
    const void* __restrict__ Wv, const void* __restrict__ bv,
    float* __restrict__ Q, float* __restrict__ K, float* __restrict__ V,
    const int* __restrict__ flagp)
{
    __shared__ float As[64][17];
    __shared__ float Bs[16][65];
    const int F   = *flagp;
    const int tid = threadIdx.x;
    const int n0  = blockIdx.x * 64;      // 0..3071
    const int m0  = blockIdx.y * 64;
    const int mat = n0 >> 10;             // 0=Q 1=K 2=V
    const int col0 = n0 & 1023;
    const void* W    = (mat == 0) ? Wq : (mat == 1) ? Wk : Wv;
    const void* bias = (mat == 0) ? bq : (mat == 1) ? bk : bv;
    float* Out = (mat == 0) ? Q : (mat == 1) ? K : V;

    const int tx = tid & 15, ty = tid >> 4;
    float acc[4][4] = {};

    for (int k0 = 0; k0 < HIDC; k0 += 16) {
        {
            const int r  = tid >> 2;
            const int kk = (tid & 3) * 4;
            const int base = (m0 + r) * HIDC + k0 + kk;
            #pragma unroll
            for (int j = 0; j < 4; ++j) As[r][kk + j] = ldin(x, base + j, F);
        }
        {
            const int c  = tid & 63;
            const int kb = tid >> 6;
            #pragma unroll
            for (int j = 0; j < 4; ++j) {
                const int kk = kb + j * 4;
                Bs[kk][c] = ldin(W, (k0 + kk) * HIDC + col0 + c, F);
            }
        }
        __syncthreads();
        #pragma unroll
        for (int kk = 0; kk < 16; ++kk) {
            float a[4], b[4];
            #pragma unroll
            for (int i = 0; i < 4; ++i) a[i] = As[ty * 4 + i][kk];
            #pragma unroll
            for (int j = 0; j < 4; ++j) b[j] = Bs[kk][tx * 4 + j];
            #pragma unroll
            for (int i = 0; i < 4; ++i)
                #pragma unroll
                for (int j = 0; j < 4; ++j)
                    acc[i][j] = fmaf(a[i], b[j], acc[i][j]);
        }
        __syncthreads();
    }
    #pragma unroll
    for (int i = 0; i < 4; ++i) {
        const int m = m0 + ty * 4 + i;
        #pragma unroll
        for (int j = 0; j < 4; ++j) {
            const int c = col0 + tx * 4 + j;
            Out[m * HIDC + c] = acc[i][j] + ldin(bias, c, F);
        }
    }
}

// ---------------- K2: rfft(64) + amplitude normalization ----------------
__global__ __launch_bounds__(64) void spectral_kernel(
    const float* __restrict__ Q, const float* __restrict__ K,
    float* __restrict__ Qn, float* __restrict__ Kn)
{
    __shared__ float qv[64];
    __shared__ float tc[64], tsn[64];
    const int unit = blockIdx.x;          // s*16 + h
    const int sel  = blockIdx.y;          // 0: Q, 1: K
    const int s = unit >> 4, h = unit & 15;
    const float* src = sel ? K : Q;
    float* dst = sel ? Kn : Qn;
    const int t = threadIdx.x;

    qv[t] = src[s * HIDC + h * HDIM + t];
    float sv, cv;
    sincosf((float)t * (6.283185307179586f / 64.0f), &sv, &cv);
    tc[t] = cv; tsn[t] = sv;
    __syncthreads();

    if (t < NFREQ) {
        float re = 0.0f, im = 0.0f;
        #pragma unroll
        for (int k = 0; k < 64; ++k) {
            const int idx = (t * k) & 63;
            re = fmaf(qv[k], tc[idx], re);
            im = fmaf(qv[k], -tsn[idx], im);   // X_f = sum x_t e^{-2pi i f t/64}
        }
        const float a  = sqrtf(re * re + im * im);
        const float sc = (a > 0.0f) ? rsqrtf(a) : 0.0f;
        const int base = (h * SEQ + s) * NF2V;
        dst[base + t]         = re * sc;
        dst[base + NFREQ + t] = im * sc;
    }
}

// ---------------- K3: attention (scores=Q~.K~*temp, softmax, PV) ----------------
__global__ __launch_bounds__(256) void attn_kernel(
    const float* __restrict__ Qn, const float* __restrict__ Kn,
    const float* __restrict__ V, const int* __restrict__ mask,
    const void* __restrict__ temp_p, float* __restrict__ ctx,
    const int* __restrict__ flagp)
{
    __shared__ float qn[8][NF2V];
    __shared__ float sc[8][SEQ];
    __shared__ float kt[64 * 67];
    __shared__ float red[4][8][64];
    __shared__ float rowsum[8];

    const int F   = *flagp;
    const int tid = threadIdx.x;
    const int h   = blockIdx.y;
    const int q0  = blockIdx.x * 8;
    const float temp = ldin(temp_p, 0, F);

    for (int idx = tid; idx < 8 * NF2V; idx += 256) {
        const int r = idx / NF2V, f = idx % NF2V;
        qn[r][f] = Qn[(h * SEQ + q0 + r) * NF2V + f];
    }
    __syncthreads();

    for (int kt0 = 0; kt0 < SEQ; kt0 += 64) {
        for (int idx = tid; idx < 64 * NF2V; idx += 256) {
            const int kk = idx / NF2V, f = idx % NF2V;
            kt[kk * 67 + f] = Kn[(h * SEQ + kt0 + kk) * NF2V + f];
        }
        __syncthreads();
        #pragma unroll
        for (int it = 0; it < 2; ++it) {
            const int item = tid + it * 256;
            const int r = item >> 6, kk = item & 63;
            float d = 0.0f;
            #pragma unroll
            for (int f = 0; f < NF2V; ++f) d = fmaf(qn[r][f], kt[kk * 67 + f], d);
            const int kabs = kt0 + kk;
            float sco = d * temp;
            if (mask[kabs] == 0) sco = -1e9f;
            sc[r][kabs] = sco;
        }
        __syncthreads();
    }

    const int w = tid >> 6, lane = tid & 63;
    for (int rr = 0; rr < 2; ++rr) {
        const int r = w * 2 + rr;
        float m = -1e30f;
        for (int k = lane; k < SEQ; k += 64) m = fmaxf(m, sc[r][k]);
        #pragma unroll
        for (int off = 32; off > 0; off >>= 1) m = fmaxf(m, __shfl_xor(m, off, 64));
        float sum = 0.0f;
        for (int k = lane; k < SEQ; k += 64) {
            const float e = __expf(sc[r][k] - m);
            sc[r][k] = e;
            sum += e;
        }
        #pragma unroll
        for (int off = 32; off > 0; off >>= 1) sum += __shfl_xor(sum, off, 64);
        if (lane == 0) rowsum[r] = sum;
    }
    __syncthreads();

    {
        const int d = tid & 63, c = tid >> 6;
        float acc[8] = {};
        const float* vcol = V + h * HDIM + d;
        for (int k = c * 128; k < c * 128 + 128; ++k) {
            const float v = vcol[k * HIDC];
            #pragma unroll
            for (int r = 0; r < 8; ++r) acc[r] = fmaf(sc[r][k], v, acc[r]);
        }
        #pragma unroll
        for (int r = 0; r < 8; ++r) red[c][r][d] = acc[r];
    }
    __syncthreads();
    #pragma unroll
    for (int p = 0; p < 2; ++p) {
        const int item = tid + p * 256;
        const int r = item >> 6, dd = item & 63;
        const float sum4 = red[0][r][dd] + red[1][r][dd] + red[2][r][dd] + red[3][r][dd];
        ctx[(q0 + r) * HIDC + h * HDIM + dd] = sum4 / rowsum[r];
    }
}

// ---------------- K4: O-projection + bias + residual -> Y (fp32) ----------------
__global__ __launch_bounds__(256) void oproj_kernel(
    const float* __restrict__ A, const void* __restrict__ W,
    const void* __restrict__ bias, const void* __restrict__ x,
    float* __restrict__ Y, const int* __restrict__ flagp)
{
    __shared__ float As[64][17];
    __shared__ float Bs[16][65];
    const int F   = *flagp;
    const int tid = threadIdx.x;
    const int n0 = blockIdx.x * 64;
    const int m0 = blockIdx.y * 64;
    const int tx = tid & 15, ty = tid >> 4;
    float acc[4][4] = {};

    for (int k0 = 0; k0 < HIDC; k0 += 16) {
        {
            const int r  = tid >> 2;
            const int kk = (tid & 3) * 4;
            const float* ap = A + (m0 + r) * HIDC + k0 + kk;
            #pragma unroll
            for (int j = 0; j < 4; ++j) As[r][kk + j] = ap[j];
        }
        {
            const int c  = tid & 63;
            const int kb = tid >> 6;
            #pragma unroll
            for (int j = 0; j < 4; ++j) {
                const int kk = kb + j * 4;
                Bs[kk][c] = ldin(W, (k0 + kk) * HIDC + n0 + c, F);
            }
        }
        __syncthreads();
        #pragma unroll
        for (int kk = 0; kk < 16; ++kk) {
            float a[4], b[4];
            #pragma unroll
            for (int i = 0; i < 4; ++i) a[i] = As[ty * 4 + i][kk];
            #pragma unroll
            for (int j = 0; j < 4; ++j) b[j] = Bs[kk][tx * 4 + j];
            #pragma unroll
            for (int i = 0; i < 4; ++i)
                #pragma unroll
                for (int j = 0; j < 4; ++j)
                    acc[i][j] = fmaf(a[i], b[j], acc[i][j]);
        }
        __syncthreads();
    }
    #pragma unroll
    for (int i = 0; i < 4; ++i) {
        const int m = m0 + ty * 4 + i;
        #pragma unroll
        for (int j = 0; j < 4; ++j) {
            const int c = n0 + tx * 4 + j;
            Y[m * HIDC + c] = acc[i][j] + ldin(bias, c, F) + ldin(x, m * HIDC + c, F);
        }
    }
}

// ---------------- K5: LayerNorm -> out (dtype per flag) ----------------
__global__ __launch_bounds__(256) void ln_kernel(
    const float* __restrict__ Y, const void* __restrict__ gamma,
    const void* __restrict__ beta, void* __restrict__ out,
    const int* __restrict__ flagp)
{
    const int F = *flagp;
    const int row = blockIdx.x, tid = threadIdx.x;
    float v[4];
    float s = 0.0f, s2 = 0.0f;
    #pragma unroll
    for (int j = 0; j < 4; ++j) {
        v[j] = Y[row * HIDC + tid + j * 256];
        s += v[j]; s2 += v[j] * v[j];
    }
    #pragma unroll
    for (int off = 32; off > 0; off >>= 1) {
        s  += __shfl_xor(s, off, 64);
        s2 += __shfl_xor(s2, off, 64);
    }
    __shared__ float wred[4][2];
    const int w = tid >> 6;
    if ((tid & 63) == 0) { wred[w][0] = s; wred[w][1] = s2; }
    __syncthreads();
    s  = wred[0][0] + wred[1][0] + wred[2][0] + wred[3][0];
    s2 = wred[0][1] + wred[1][1] + wred[2][1] + wred[3][1];
    const float mu   = s / (float)HIDC;
    const float var  = s2 / (float)HIDC - mu * mu;
    const float rstd = rsqrtf(var + 1e-5f);
    #pragma unroll
    for (int j = 0; j < 4; ++j) {
        const int c = tid + j * 256;
        const float g = ldin(gamma, c, F), b = ldin(beta, c, F);
        const float r = (v[j] - mu) * rstd * g + b;
        if (F) ((float*)out)[row * HIDC + c] = r;
        else   ((__hip_bfloat16*)out)[row * HIDC + c] = __float2bfloat16(r);
    }
}

extern "C" void kernel_launch(void* const* d_in, const int* in_sizes, int n_in,
                              void* d_out, int out_size, void* d_ws, size_t ws_size,
                              hipStream_t stream) {
    const void* x    = d_in[0];
    const int*  mask = (const int*)d_in[1];
    const void* Wq   = d_in[2];
    const void* bq   = d_in[3];
    const void* Wk   = d_in[4];
    const void* bk   = d_in[5];
    const void* Wv   = d_in[6];
    const void* bv   = d_in[7];
    const void* Wo   = d_in[8];
    const void* bo   = d_in[9];
    const void* temp = d_in[10];
    const void* gam  = d_in[11];
    const void* bet  = d_in[12];

    float* ws   = (float*)d_ws;
    int*   flag = (int*)ws;                  // 4 floats reserved (16B align)
    float* Q    = ws + 4;                    // 512*1024
    float* K    = Q   + SEQ * HIDC;
    float* V    = K   + SEQ * HIDC;
    float* Qn   = V   + SEQ * HIDC;          // 16*512*66
    float* Kn   = Qn  + NH * SEQ * NF2V;
    float* ctx  = Kn  + NH * SEQ * NF2V;     // 512*1024
    float* Y    = ctx + SEQ * HIDC;          // 512*1024

    sniff_kernel<<<1, 256, 0, stream>>>(Wq, flag);
    qkv_kernel<<<dim3(48, 8), 256, 0, stream>>>(x, Wq, bq, Wk, bk, Wv, bv, Q, K, V, flag);
    spectral_kernel<<<dim3(SEQ * NH, 2), 64, 0, stream>>>(Q, K, Qn, Kn);
    attn_kernel<<<dim3(SEQ / 8, NH), 256, 0, stream>>>(Qn, Kn, V, mask, temp, ctx, flag);
    oproj_kernel<<<dim3(16, 8), 256, 0, stream>>>(ctx, Wo, bo, x, Y, flag);
    ln_kernel<<<SEQ, 256, 0, stream>>>(Y, gam, bet, d_out, flag);
}